// Round 1
// baseline (15413.101 us; speedup 1.0000x reference)
//
#include <hip/hip_runtime.h>

// ---------------------------------------------------------------------------
// ManualLSTM: B=32, S=512, H=1024.
//   Phase A: xg = bf16(x) @ bf16(Wi) + (bias in epilogue)  -> bf16 [16384][4096]
//   Phase B: persistent 128-block kernel, 512 timesteps, flag-array barrier.
// ---------------------------------------------------------------------------

typedef __attribute__((ext_vector_type(4))) float f32x4_t;
typedef __attribute__((ext_vector_type(8))) short bf16x8_t;

#define HID   1024
#define SLEN  512
#define BATCH 32
#define NGATE 4096
#define MROWS 16384          // 32*512

// ws layout (bytes)
#define XG_OFF    0ULL                      // 16384*4096*2 = 134217728
#define XB_OFF    134217728ULL              // 16384*1024*2 = 33554432
#define WIT_OFF   167772160ULL              // 4096*1024*2  = 8388608
#define WHT_OFF   176160768ULL              // 4096*1024*2  = 8388608
#define HBUF_OFF  184549376ULL              // 2 * 66048
#define FLAGS_OFF 184681472ULL              // 128 * 4
// total ~176.2 MB required in d_ws

#define HROW_STRIDE 2064                    // 1024 bf16 (2048B) + 16B pad
#define HIMG        (32 * HROW_STRIDE)      // 66048
#define NBLK_B      128                     // persistent blocks

__device__ __forceinline__ unsigned short f2bf(float f) {
  unsigned u = __float_as_uint(f);
  u += 0x7fffu + ((u >> 16) & 1u);          // round-nearest-even
  return (unsigned short)(u >> 16);
}
__device__ __forceinline__ float bf2f(unsigned short u) {
  return __uint_as_float(((unsigned)u) << 16);
}
__device__ __forceinline__ float fast_rcp(float x) { return __builtin_amdgcn_rcpf(x); }
__device__ __forceinline__ float sigmoid_f(float x) { return fast_rcp(1.f + __expf(-x)); }
__device__ __forceinline__ float tanh_f(float x) { return 1.f - 2.f * fast_rcp(1.f + __expf(2.f * x)); }

// ---------------------------------------------------------------- converters
__global__ __launch_bounds__(256) void conv_x_bf16(const float* __restrict__ in,
                                                   unsigned short* __restrict__ out) {
  // 16,777,216 floats = 4,194,304 float4; grid 16384 x 256
  size_t i = (size_t)blockIdx.x * 256 + threadIdx.x;
  const float4* p = (const float4*)in;
  float4 v = p[i];
  ushort4 o;
  o.x = f2bf(v.x); o.y = f2bf(v.y); o.z = f2bf(v.z); o.w = f2bf(v.w);
  ((ushort4*)out)[i] = o;
}

// in: fp32 [1024][4096]  -> out: bf16 [4096][1024]  (out[n][k] = in[k][n])
__global__ void transpose_w_bf16(const float* __restrict__ in,
                                 unsigned short* __restrict__ out) {
  __shared__ float tile[32][33];
  int tx = threadIdx.x, ty = threadIdx.y;        // block (32, 8)
  int n0 = blockIdx.x * 32, k0 = blockIdx.y * 32;
  #pragma unroll
  for (int i = 0; i < 4; i++)
    tile[ty + 8 * i][tx] = in[(size_t)(k0 + ty + 8 * i) * NGATE + n0 + tx];
  __syncthreads();
  #pragma unroll
  for (int i = 0; i < 4; i++)
    out[(size_t)(n0 + ty + 8 * i) * HID + k0 + tx] = f2bf(tile[tx][ty + 8 * i]);
}

__global__ void init_ws(unsigned* __restrict__ himg0, unsigned* __restrict__ flags) {
  size_t i = (size_t)blockIdx.x * 256 + threadIdx.x;
  for (size_t k = i; k < HIMG / 4; k += (size_t)gridDim.x * 256) himg0[k] = 0u;
  if (i < NBLK_B) flags[i] = 0u;
}

// ---------------------------------------------------------------- Phase A
// C[16384][4096] bf16 = A[16384][1024] bf16  x  BT[4096][1024] bf16 (+bias)
__global__ __launch_bounds__(256) void gemm_xg(const unsigned short* __restrict__ A,
                                               const unsigned short* __restrict__ BT,
                                               const float* __restrict__ bias,
                                               unsigned short* __restrict__ C) {
  extern __shared__ char smem[];
  char* As = smem;                 // 128 rows * 80B (32 bf16 + 16B pad)
  char* Bs = smem + 10240;         // 128 rows * 80B
  const int tid = threadIdx.x;
  const int lane = tid & 63, w = tid >> 6, q = lane >> 4, l16 = lane & 15;
  const int wm = w & 1, wn = w >> 1;
  const size_t m0 = (size_t)blockIdx.y * 128, n0 = (size_t)blockIdx.x * 128;

  f32x4_t acc[4][4];
  #pragma unroll
  for (int i = 0; i < 4; i++)
    #pragma unroll
    for (int j = 0; j < 4; j++) acc[i][j] = (f32x4_t){0.f, 0.f, 0.f, 0.f};

  float bfr[4];
  #pragma unroll
  for (int nt = 0; nt < 4; nt++) bfr[nt] = bias[n0 + wn * 64 + nt * 16 + l16];

  for (int kk = 0; kk < 32; kk++) {
    const int k0 = kk * 32;
    #pragma unroll
    for (int h = 0; h < 2; h++) {
      int idx = tid + h * 256;              // 0..511
      int r = idx >> 2, ch = idx & 3;
      uint4 va = *(const uint4*)((const char*)A + ((m0 + r) * HID + k0) * 2 + ch * 16);
      *(uint4*)(As + r * 80 + ch * 16) = va;
      uint4 vb = *(const uint4*)((const char*)BT + ((n0 + r) * HID + k0) * 2 + ch * 16);
      *(uint4*)(Bs + r * 80 + ch * 16) = vb;
    }
    __syncthreads();
    bf16x8_t af[4], bf[4];
    #pragma unroll
    for (int mt = 0; mt < 4; mt++)
      af[mt] = *(const bf16x8_t*)(As + (wm * 64 + mt * 16 + l16) * 80 + q * 16);
    #pragma unroll
    for (int nt = 0; nt < 4; nt++)
      bf[nt] = *(const bf16x8_t*)(Bs + (wn * 64 + nt * 16 + l16) * 80 + q * 16);
    #pragma unroll
    for (int mt = 0; mt < 4; mt++)
      #pragma unroll
      for (int nt = 0; nt < 4; nt++)
        acc[mt][nt] = __builtin_amdgcn_mfma_f32_16x16x32_bf16(af[mt], bf[nt], acc[mt][nt], 0, 0, 0);
    __syncthreads();
  }

  // epilogue: stage C tile (bf16 [128][136]) through LDS for coalesced stores
  unsigned short* cst = (unsigned short*)smem;
  #pragma unroll
  for (int mt = 0; mt < 4; mt++)
    #pragma unroll
    for (int nt = 0; nt < 4; nt++)
      #pragma unroll
      for (int r = 0; r < 4; r++) {
        int m = wm * 64 + mt * 16 + q * 4 + r;
        int n = wn * 64 + nt * 16 + l16;
        cst[m * 136 + n] = f2bf(acc[mt][nt][r] + bfr[nt]);
      }
  __syncthreads();
  #pragma unroll
  for (int i = 0; i < 8; i++) {
    int idx = tid + i * 256;                // < 2048
    int row = idx >> 4, ch = idx & 15;
    uint4 v = *(const uint4*)((const char*)cst + row * 272 + ch * 16);
    *(uint4*)((char*)C + ((m0 + row) * NGATE + n0) * 2 + ch * 16) = v;
  }
}

// ---------------------------------------------------------------- Phase B
// Persistent recurrence. 128 blocks x 256 threads. Block owns 8 h-columns.
// LDS: Wh slice 32x2064 (66048) | h image 32x2064 (66048) | gates 32x32 f32 (4096)
__global__ __launch_bounds__(256) void lstm_persistent(
    const unsigned short* __restrict__ xg,   // [16384][4096] bf16
    const unsigned short* __restrict__ whT,  // [4096][1024] bf16
    const float* __restrict__ bias,          // [4096]
    float* __restrict__ out,                 // [32][512][1024]
    unsigned short* __restrict__ hbuf,       // 2 images, HIMG bytes each
    unsigned* __restrict__ flags) {          // [128]
  extern __shared__ char smem[];
  char* w_lds = smem;
  char* h_lds = smem + HIMG;
  float* gates = (float*)(smem + 2 * HIMG);  // [b][n] 32x32

  const int tid = threadIdx.x;
  const int lane = tid & 63, w = tid >> 6, q = lane >> 4, l16 = lane & 15;
  const int Mt = w & 1, Nt = w >> 1;
  const int hcol0 = blockIdx.x * 8;
  const int b_ew = tid >> 3, j_ew = tid & 7;

  // pin Wh slice in LDS: lds row n (= g*8+j) <- whT row g*1024 + hcol0 + j
  for (int idx = tid; idx < 32 * 128; idx += 256) {
    int n = idx >> 7, ch = idx & 127;
    size_t gr = (size_t)((n >> 3) << 10) + hcol0 + (n & 7);
    uint4 v = *(const uint4*)((const char*)whT + gr * 2048 + ch * 16);
    *(uint4*)(w_lds + n * HROW_STRIDE + ch * 16) = v;
  }
  float bs[4];
  #pragma unroll
  for (int g = 0; g < 4; g++) bs[g] = bias[g * 1024 + hcol0 + j_ew];
  float c_st = 0.f;
  __syncthreads();

  for (int t = 0; t < SLEN; t++) {
    // prefetch xg for this step (no dependency on h) while the barrier drains
    unsigned short xgv[4];
    {
      const unsigned short* p = xg + ((size_t)((b_ew << 9) + t) << 12) + hcol0 + j_ew;
      xgv[0] = p[0]; xgv[1] = p[1024]; xgv[2] = p[2048]; xgv[3] = p[3072];
    }
    if (t > 0) {
      if (tid < NBLK_B) {
        while (__hip_atomic_load(flags + tid, __ATOMIC_RELAXED, __HIP_MEMORY_SCOPE_AGENT) < (unsigned)t)
          __builtin_amdgcn_s_sleep(1);
      }
      __syncthreads();
      __threadfence();   // acquire: invalidate stale L1/L2 before reading h
    }
    // stage h image (linear copy, producers wrote it in this exact layout)
    const char* src = (const char*)hbuf + (size_t)(t & 1) * HIMG;
    for (int idx = tid; idx < HIMG / 16; idx += 256)
      *(uint4*)(h_lds + idx * 16) = *(const uint4*)(src + idx * 16);
    __syncthreads();

    // gates[b][n] = sum_k h[b][k] * Wslice[k][n]
    f32x4_t acc0 = (f32x4_t){0.f, 0.f, 0.f, 0.f};
    f32x4_t acc1 = (f32x4_t){0.f, 0.f, 0.f, 0.f};
    const char* arow = h_lds + (Mt * 16 + l16) * HROW_STRIDE + q * 16;
    const char* brow = w_lds + (Nt * 16 + l16) * HROW_STRIDE + q * 16;
    #pragma unroll
    for (int kk = 0; kk < 32; kk += 2) {
      bf16x8_t a0 = *(const bf16x8_t*)(arow + kk * 64);
      bf16x8_t b0 = *(const bf16x8_t*)(brow + kk * 64);
      acc0 = __builtin_amdgcn_mfma_f32_16x16x32_bf16(a0, b0, acc0, 0, 0, 0);
      bf16x8_t a1 = *(const bf16x8_t*)(arow + kk * 64 + 64);
      bf16x8_t b1 = *(const bf16x8_t*)(brow + kk * 64 + 64);
      acc1 = __builtin_amdgcn_mfma_f32_16x16x32_bf16(a1, b1, acc1, 0, 0, 0);
    }
    #pragma unroll
    for (int r = 0; r < 4; r++) {
      int bb = Mt * 16 + q * 4 + r;
      int nn = Nt * 16 + l16;
      gates[bb * 32 + nn] = acc0[r] + acc1[r];
    }
    __syncthreads();

    // elementwise: thread owns (b_ew, j_ew)
    float gi = gates[b_ew * 32 + j_ew]      + bs[0] + bf2f(xgv[0]);
    float gf = gates[b_ew * 32 + 8 + j_ew]  + bs[1] + bf2f(xgv[1]);
    float gg = gates[b_ew * 32 + 16 + j_ew] + bs[2] + bf2f(xgv[2]);
    float go = gates[b_ew * 32 + 24 + j_ew] + bs[3] + bf2f(xgv[3]);
    float i_s = sigmoid_f(gi), f_s = sigmoid_f(gf);
    float g_t = tanh_f(gg), o_s = sigmoid_f(go);
    c_st = f_s * c_st + i_s * g_t;
    float h = o_s * tanh_f(c_st);
    out[((size_t)b_ew * SLEN + t) * HID + hcol0 + j_ew] = h;
    *(unsigned short*)((char*)hbuf + (size_t)((t + 1) & 1) * HIMG +
                       b_ew * HROW_STRIDE + (hcol0 + j_ew) * 2) = f2bf(h);

    __threadfence();     // release: publish h + out before flag
    __syncthreads();     // all threads of the block have published
    if (tid == 0)
      __hip_atomic_store(flags + blockIdx.x, (unsigned)(t + 1),
                         __ATOMIC_RELEASE, __HIP_MEMORY_SCOPE_AGENT);
  }
}

// ---------------------------------------------------------------- launcher
extern "C" void kernel_launch(void* const* d_in, const int* in_sizes, int n_in,
                              void* d_out, int out_size, void* d_ws, size_t ws_size,
                              hipStream_t stream) {
  const float* x    = (const float*)d_in[0];   // [32,512,1024]
  const float* wi   = (const float*)d_in[1];   // [1024,4096]
  const float* wh   = (const float*)d_in[2];   // [1024,4096]
  const float* bias = (const float*)d_in[3];   // [4096]
  float* out = (float*)d_out;

  char* ws = (char*)d_ws;
  unsigned short* xg   = (unsigned short*)(ws + XG_OFF);
  unsigned short* xb   = (unsigned short*)(ws + XB_OFF);
  unsigned short* wiT  = (unsigned short*)(ws + WIT_OFF);
  unsigned short* whT  = (unsigned short*)(ws + WHT_OFF);
  unsigned short* hbuf = (unsigned short*)(ws + HBUF_OFF);
  unsigned* flags      = (unsigned*)(ws + FLAGS_OFF);

  // allow >64KB dynamic LDS for the persistent kernel (ignore failure)
  static bool attr_set = false;
  if (!attr_set) {
    (void)hipFuncSetAttribute((const void*)lstm_persistent,
                              hipFuncAttributeMaxDynamicSharedMemorySize,
                              2 * HIMG + 4096);
    attr_set = true;
  }

  conv_x_bf16<<<16384, 256, 0, stream>>>(x, xb);
  transpose_w_bf16<<<dim3(128, 32), dim3(32, 8), 0, stream>>>(wi, wiT);
  transpose_w_bf16<<<dim3(128, 32), dim3(32, 8), 0, stream>>>(wh, whT);
  init_ws<<<64, 256, 0, stream>>>((unsigned*)hbuf, flags);
  gemm_xg<<<dim3(32, 128), 256, 34816, stream>>>(xb, wiT, bias, xg);
  lstm_persistent<<<NBLK_B, 256, 2 * HIMG + 4096, stream>>>(xg, whT, bias, out, hbuf, flags);
}

// Round 2
// 4278.469 us; speedup vs baseline: 3.6025x; 3.6025x over previous
//
#include <hip/hip_runtime.h>

// ---------------------------------------------------------------------------
// ManualLSTM: B=32, S=512, H=1024.
//   Phase A: xg = bf16(x) @ bf16(Wi)  -> bf16 [16384][4096]  (bias in phase B)
//   Phase B: persistent 128-block kernel, 512 timesteps.
//     Cross-block h exchange via relaxed AGENT-scope atomics (sc0 sc1, LLC-
//     coherent) — NO __threadfence (its buffer_wbl2/buffer_inv L2 walks were
//     the 29.5us/step stall in R0). Single agent-RELEASE flag store per step.
// ---------------------------------------------------------------------------

typedef __attribute__((ext_vector_type(4))) float f32x4_t;
typedef __attribute__((ext_vector_type(8))) short bf16x8_t;
typedef unsigned long long ull_t;

#define HID   1024
#define SLEN  512
#define BATCH 32
#define NGATE 4096
#define MROWS 16384          // 32*512

// ws layout (bytes)
#define XG_OFF    0ULL                      // 16384*4096*2 = 134217728
#define XB_OFF    134217728ULL              // 16384*1024*2 = 33554432
#define WIT_OFF   167772160ULL              // 4096*1024*2  = 8388608
#define WHT_OFF   176160768ULL              // 4096*1024*2  = 8388608
#define HBUF_OFF  184549376ULL              // 2 * 65536 (packed bf16 [32][1024])
#define FLAGS_OFF 184680448ULL              // 128 * 4
// total ~184.7 MB required in d_ws

#define HIMG_G      65536                   // packed global h image: 32*1024*2
#define HROW_STRIDE 2064                    // LDS: 2048B row + 16B pad (2-way-free MFMA reads)
#define NBLK_B      128                     // persistent blocks

// persistent-kernel LDS layout
#define W_OFF_L   0
#define H_OFF_L   66048                     // 32*2064
#define G_OFF_L   132096                    // gates: 32 rows * 33 f32 = 4224B
#define HS_OFF_L  136320                    // h staging: 32*8*2B = 512B
#define LDS_TOTAL 136832

__device__ __forceinline__ unsigned short f2bf(float f) {
  unsigned u = __float_as_uint(f);
  u += 0x7fffu + ((u >> 16) & 1u);          // round-nearest-even
  return (unsigned short)(u >> 16);
}
__device__ __forceinline__ float bf2f(unsigned short u) {
  return __uint_as_float(((unsigned)u) << 16);
}
__device__ __forceinline__ float fast_rcp(float x) { return __builtin_amdgcn_rcpf(x); }
__device__ __forceinline__ float sigmoid_f(float x) { return fast_rcp(1.f + __expf(-x)); }
__device__ __forceinline__ float tanh_f(float x) { return 1.f - 2.f * fast_rcp(1.f + __expf(2.f * x)); }

// ---------------------------------------------------------------- converters
__global__ __launch_bounds__(256) void conv_x_bf16(const float* __restrict__ in,
                                                   unsigned short* __restrict__ out) {
  size_t i = (size_t)blockIdx.x * 256 + threadIdx.x;
  const float4* p = (const float4*)in;
  float4 v = p[i];
  ushort4 o;
  o.x = f2bf(v.x); o.y = f2bf(v.y); o.z = f2bf(v.z); o.w = f2bf(v.w);
  ((ushort4*)out)[i] = o;
}

// in: fp32 [1024][4096]  -> out: bf16 [4096][1024]  (out[n][k] = in[k][n])
__global__ void transpose_w_bf16(const float* __restrict__ in,
                                 unsigned short* __restrict__ out) {
  __shared__ float tile[32][33];
  int tx = threadIdx.x, ty = threadIdx.y;        // block (32, 8)
  int n0 = blockIdx.x * 32, k0 = blockIdx.y * 32;
  #pragma unroll
  for (int i = 0; i < 4; i++)
    tile[ty + 8 * i][tx] = in[(size_t)(k0 + ty + 8 * i) * NGATE + n0 + tx];
  __syncthreads();
  #pragma unroll
  for (int i = 0; i < 4; i++)
    out[(size_t)(n0 + ty + 8 * i) * HID + k0 + tx] = f2bf(tile[tx][ty + 8 * i]);
}

__global__ void init_ws(unsigned* __restrict__ himg0, unsigned* __restrict__ flags) {
  size_t i = (size_t)blockIdx.x * 256 + threadIdx.x;   // 16384 threads
  himg0[i] = 0u;                                       // HIMG_G/4 = 16384 dwords
  if (i < NBLK_B) flags[i] = 0u;
}

// ---------------------------------------------------------------- Phase A
// C[16384][4096] bf16 = A[16384][1024] bf16  x  BT[4096][1024] bf16
__global__ __launch_bounds__(256) void gemm_xg(const unsigned short* __restrict__ A,
                                               const unsigned short* __restrict__ BT,
                                               unsigned short* __restrict__ C) {
  extern __shared__ char smem[];
  char* As = smem;                 // 128 rows * 80B (32 bf16 + 16B pad)
  char* Bs = smem + 10240;
  const int tid = threadIdx.x;
  const int lane = tid & 63, w = tid >> 6, q = lane >> 4, l16 = lane & 15;
  const int wm = w & 1, wn = w >> 1;
  const size_t m0 = (size_t)blockIdx.y * 128, n0 = (size_t)blockIdx.x * 128;

  f32x4_t acc[4][4];
  #pragma unroll
  for (int i = 0; i < 4; i++)
    #pragma unroll
    for (int j = 0; j < 4; j++) acc[i][j] = (f32x4_t){0.f, 0.f, 0.f, 0.f};

  for (int kk = 0; kk < 32; kk++) {
    const int k0 = kk * 32;
    #pragma unroll
    for (int h = 0; h < 2; h++) {
      int idx = tid + h * 256;              // 0..511
      int r = idx >> 2, ch = idx & 3;
      uint4 va = *(const uint4*)((const char*)A + ((m0 + r) * HID + k0) * 2 + ch * 16);
      *(uint4*)(As + r * 80 + ch * 16) = va;
      uint4 vb = *(const uint4*)((const char*)BT + ((n0 + r) * HID + k0) * 2 + ch * 16);
      *(uint4*)(Bs + r * 80 + ch * 16) = vb;
    }
    __syncthreads();
    bf16x8_t af[4], bf[4];
    #pragma unroll
    for (int mt = 0; mt < 4; mt++)
      af[mt] = *(const bf16x8_t*)(As + (wm * 64 + mt * 16 + l16) * 80 + q * 16);
    #pragma unroll
    for (int nt = 0; nt < 4; nt++)
      bf[nt] = *(const bf16x8_t*)(Bs + (wn * 64 + nt * 16 + l16) * 80 + q * 16);
    #pragma unroll
    for (int mt = 0; mt < 4; mt++)
      #pragma unroll
      for (int nt = 0; nt < 4; nt++)
        acc[mt][nt] = __builtin_amdgcn_mfma_f32_16x16x32_bf16(af[mt], bf[nt], acc[mt][nt], 0, 0, 0);
    __syncthreads();
  }

  // epilogue: stage C tile (bf16 [128][136]) through LDS for coalesced stores
  unsigned short* cst = (unsigned short*)smem;
  #pragma unroll
  for (int mt = 0; mt < 4; mt++)
    #pragma unroll
    for (int nt = 0; nt < 4; nt++)
      #pragma unroll
      for (int r = 0; r < 4; r++) {
        int m = wm * 64 + mt * 16 + q * 4 + r;
        int n = wn * 64 + nt * 16 + l16;
        cst[m * 136 + n] = f2bf(acc[mt][nt][r]);
      }
  __syncthreads();
  #pragma unroll
  for (int i = 0; i < 8; i++) {
    int idx = tid + i * 256;                // < 2048
    int row = idx >> 4, ch = idx & 15;
    uint4 v = *(const uint4*)((const char*)cst + row * 272 + ch * 16);
    *(uint4*)((char*)C + ((m0 + row) * NGATE + n0) * 2 + ch * 16) = v;
  }
}

// ---------------------------------------------------------------- Phase B
// Persistent recurrence. 128 blocks x 256 threads. Block owns 8 h-columns.
__global__ __launch_bounds__(256) void lstm_persistent(
    const unsigned short* __restrict__ xg,   // [16384][4096] bf16
    const unsigned short* __restrict__ whT,  // [4096][1024] bf16
    const float* __restrict__ bias,          // [4096]
    float* __restrict__ out,                 // [32][512][1024]
    unsigned short* hbuf,                    // 2 packed images, 65536B each
    unsigned* flags) {                       // [128]
  extern __shared__ char smem[];
  char* w_lds = smem + W_OFF_L;
  char* h_lds = smem + H_OFF_L;
  float* gates = (float*)(smem + G_OFF_L);         // [32][33] f32
  unsigned short* hstage = (unsigned short*)(smem + HS_OFF_L);  // [32][8] bf16

  const int tid = threadIdx.x;
  const int lane = tid & 63, w = tid >> 6, q = lane >> 4, l16 = lane & 15;
  const int Mt = w & 1, Nt = w >> 1;
  const int hcol0 = blockIdx.x * 8;
  const int b_ew = tid >> 3, j_ew = tid & 7;

  // pin Wh slice in LDS: lds row n (= g*8+j) <- whT row g*1024 + hcol0 + j
  for (int idx = tid; idx < 32 * 128; idx += 256) {
    int n = idx >> 7, ch = idx & 127;
    size_t gr = (size_t)((n >> 3) << 10) + hcol0 + (n & 7);
    uint4 v = *(const uint4*)((const char*)whT + gr * 2048 + ch * 16);
    *(uint4*)(w_lds + n * HROW_STRIDE + ch * 16) = v;
  }
  float bs[4];
  #pragma unroll
  for (int g = 0; g < 4; g++) bs[g] = bias[g * 1024 + hcol0 + j_ew];
  float c_st = 0.f;
  __syncthreads();

  for (int t = 0; t < SLEN; t++) {
    // prefetch xg for this step (no dependency on h) while the barrier drains
    unsigned short xgv[4];
    {
      const unsigned short* p = xg + ((size_t)((b_ew << 9) + t) << 12) + hcol0 + j_ew;
      xgv[0] = p[0]; xgv[1] = p[1024]; xgv[2] = p[2048]; xgv[3] = p[3072];
    }
    if (t > 0) {
      if (tid < NBLK_B) {
        while (__hip_atomic_load(flags + tid, __ATOMIC_RELAXED, __HIP_MEMORY_SCOPE_AGENT) < (unsigned)t)
          __builtin_amdgcn_s_sleep(1);
      }
      __syncthreads();
      // no fence: h loads below are sc0/sc1 (L1/L2-bypassing, LLC-coherent)
    }
    // gather h image via agent-scope (coherent) 8B loads -> LDS padded image
    {
      ull_t* src = (ull_t*)(hbuf + (size_t)(t & 1) * (HIMG_G / 2));
      ull_t hv[32];
      #pragma unroll
      for (int i = 0; i < 32; i++)
        hv[i] = __hip_atomic_load(src + tid + i * 256, __ATOMIC_RELAXED,
                                  __HIP_MEMORY_SCOPE_AGENT);
      #pragma unroll
      for (int i = 0; i < 32; i++) {
        int idx = tid + i * 256;
        int row = idx >> 8, c8 = idx & 255;     // 256 ull per 2048B row
        *(ull_t*)(h_lds + row * HROW_STRIDE + c8 * 8) = hv[i];
      }
    }
    __syncthreads();

    // gates[b][n] = sum_k h[b][k] * Wslice[k][n]
    f32x4_t acc0 = (f32x4_t){0.f, 0.f, 0.f, 0.f};
    f32x4_t acc1 = (f32x4_t){0.f, 0.f, 0.f, 0.f};
    const char* arow = h_lds + (Mt * 16 + l16) * HROW_STRIDE + q * 16;
    const char* brow = w_lds + (Nt * 16 + l16) * HROW_STRIDE + q * 16;
    #pragma unroll
    for (int kk = 0; kk < 32; kk += 2) {
      bf16x8_t a0 = *(const bf16x8_t*)(arow + kk * 64);
      bf16x8_t b0 = *(const bf16x8_t*)(brow + kk * 64);
      acc0 = __builtin_amdgcn_mfma_f32_16x16x32_bf16(a0, b0, acc0, 0, 0, 0);
      bf16x8_t a1 = *(const bf16x8_t*)(arow + kk * 64 + 64);
      bf16x8_t b1 = *(const bf16x8_t*)(brow + kk * 64 + 64);
      acc1 = __builtin_amdgcn_mfma_f32_16x16x32_bf16(a1, b1, acc1, 0, 0, 0);
    }
    #pragma unroll
    for (int r = 0; r < 4; r++) {
      int bb = Mt * 16 + q * 4 + r;
      int nn = Nt * 16 + l16;
      gates[bb * 33 + nn] = acc0[r] + acc1[r];
    }
    __syncthreads();

    // elementwise: thread owns (b_ew, j_ew)
    float gi = gates[b_ew * 33 + j_ew]      + bs[0] + bf2f(xgv[0]);
    float gf = gates[b_ew * 33 + 8 + j_ew]  + bs[1] + bf2f(xgv[1]);
    float gg = gates[b_ew * 33 + 16 + j_ew] + bs[2] + bf2f(xgv[2]);
    float go = gates[b_ew * 33 + 24 + j_ew] + bs[3] + bf2f(xgv[3]);
    float i_s = sigmoid_f(gi), f_s = sigmoid_f(gf);
    float g_t = tanh_f(gg), o_s = sigmoid_f(go);
    c_st = f_s * c_st + i_s * g_t;
    float h = o_s * tanh_f(c_st);
    out[((size_t)b_ew * SLEN + t) * HID + hcol0 + j_ew] = h;
    hstage[b_ew * 8 + j_ew] = f2bf(h);
    __syncthreads();

    // wave 0 publishes h (coherent 8B stores) then the flag (agent release:
    // s_waitcnt drains wave-0's sc1 stores before the flag becomes visible)
    if (tid < 64) {
      ull_t v = ((const ull_t*)hstage)[tid];
      int b = tid >> 1, half = tid & 1;
      ull_t* dst = (ull_t*)(hbuf + (size_t)((t + 1) & 1) * (HIMG_G / 2)
                            + b * HID + hcol0) + half;
      __hip_atomic_store(dst, v, __ATOMIC_RELAXED, __HIP_MEMORY_SCOPE_AGENT);
      if (tid == 0)
        __hip_atomic_store(flags + blockIdx.x, (unsigned)(t + 1),
                           __ATOMIC_RELEASE, __HIP_MEMORY_SCOPE_AGENT);
    }
  }
}

// ---------------------------------------------------------------- launcher
extern "C" void kernel_launch(void* const* d_in, const int* in_sizes, int n_in,
                              void* d_out, int out_size, void* d_ws, size_t ws_size,
                              hipStream_t stream) {
  const float* x    = (const float*)d_in[0];   // [32,512,1024]
  const float* wi   = (const float*)d_in[1];   // [1024,4096]
  const float* wh   = (const float*)d_in[2];   // [1024,4096]
  const float* bias = (const float*)d_in[3];   // [4096]
  float* out = (float*)d_out;

  char* ws = (char*)d_ws;
  unsigned short* xg   = (unsigned short*)(ws + XG_OFF);
  unsigned short* xb   = (unsigned short*)(ws + XB_OFF);
  unsigned short* wiT  = (unsigned short*)(ws + WIT_OFF);
  unsigned short* whT  = (unsigned short*)(ws + WHT_OFF);
  unsigned short* hbuf = (unsigned short*)(ws + HBUF_OFF);
  unsigned* flags      = (unsigned*)(ws + FLAGS_OFF);

  (void)hipFuncSetAttribute((const void*)lstm_persistent,
                            hipFuncAttributeMaxDynamicSharedMemorySize,
                            LDS_TOTAL);

  conv_x_bf16<<<16384, 256, 0, stream>>>(x, xb);
  transpose_w_bf16<<<dim3(128, 32), dim3(32, 8), 0, stream>>>(wi, wiT);
  transpose_w_bf16<<<dim3(128, 32), dim3(32, 8), 0, stream>>>(wh, whT);
  init_ws<<<64, 256, 0, stream>>>((unsigned*)hbuf, flags);
  gemm_xg<<<dim3(32, 128), 256, 34816, stream>>>(xb, wiT, xg);
  lstm_persistent<<<NBLK_B, 256, LDS_TOTAL, stream>>>(xg, whT, bias, out, hbuf, flags);
}

// Round 3
// 3834.502 us; speedup vs baseline: 4.0196x; 1.1158x over previous
//
#include <hip/hip_runtime.h>

// ---------------------------------------------------------------------------
// ManualLSTM: B=32, S=512, H=1024.
//   Phase A: xg = bf16(x) @ bf16(Wi)  -> bf16 [16384][4096]  (bias in phase B)
//   Phase B: persistent 128-block kernel, 512 timesteps.
//     All cross-block state (h, flags) moves via relaxed AGENT-scope atomics
//     (sc-bit, LLC-coherent). NO release/acquire atomics and NO threadfence:
//     on multi-XCD gfx950 those emit buffer_wbl2/buffer_inv L2 walks, which
//     were 6 of the 7.7 us/step in R2. Ordering = s_waitcnt vmcnt(0) +
//     barrier + relaxed flag store.
// ---------------------------------------------------------------------------

typedef __attribute__((ext_vector_type(4))) float f32x4_t;
typedef __attribute__((ext_vector_type(8))) short bf16x8_t;
typedef __attribute__((ext_vector_type(2))) unsigned long long ull2_t;
typedef unsigned long long ull_t;

#define HID   1024
#define SLEN  512
#define BATCH 32
#define NGATE 4096
#define MROWS 16384          // 32*512

// ws layout (bytes)
#define XG_OFF    0ULL                      // 16384*4096*2 = 134217728
#define XB_OFF    134217728ULL              // 16384*1024*2 = 33554432
#define WIT_OFF   167772160ULL              // 4096*1024*2  = 8388608
#define WHT_OFF   176160768ULL              // 4096*1024*2  = 8388608
#define HBUF_OFF  184549376ULL              // 2 * 65536 (packed bf16 [32][1024])
#define FLAGS_OFF 184680448ULL              // 128 flags * 16B stride = 2048B

#define HIMG_G      65536                   // packed global h image: 32*1024*2
#define HROW_STRIDE 2064                    // LDS: 2048B row + 16B pad
#define NBLK_B      128                     // persistent blocks
#define FLAG_STRIDE 4                       // in dwords (16B)

// persistent-kernel LDS layout
#define W_OFF_L   0
#define H_OFF_L   66048                     // 32*2064
#define G_OFF_L   132096                    // gates: 32 rows * 33 f32 = 4224B
#define LDS_TOTAL 136320

__device__ __forceinline__ unsigned short f2bf(float f) {
  unsigned u = __float_as_uint(f);
  u += 0x7fffu + ((u >> 16) & 1u);          // round-nearest-even
  return (unsigned short)(u >> 16);
}
__device__ __forceinline__ float bf2f(unsigned short u) {
  return __uint_as_float(((unsigned)u) << 16);
}
__device__ __forceinline__ float fast_rcp(float x) { return __builtin_amdgcn_rcpf(x); }
__device__ __forceinline__ float sigmoid_f(float x) { return fast_rcp(1.f + __expf(-x)); }
__device__ __forceinline__ float tanh_f(float x) { return 1.f - 2.f * fast_rcp(1.f + __expf(2.f * x)); }

// ---------------------------------------------------------------- converters
__global__ __launch_bounds__(256) void conv_x_bf16(const float* __restrict__ in,
                                                   unsigned short* __restrict__ out) {
  size_t i = (size_t)blockIdx.x * 256 + threadIdx.x;
  const float4* p = (const float4*)in;
  float4 v = p[i];
  ushort4 o;
  o.x = f2bf(v.x); o.y = f2bf(v.y); o.z = f2bf(v.z); o.w = f2bf(v.w);
  ((ushort4*)out)[i] = o;
}

// in: fp32 [1024][4096]  -> out: bf16 [4096][1024]  (out[n][k] = in[k][n])
__global__ void transpose_w_bf16(const float* __restrict__ in,
                                 unsigned short* __restrict__ out) {
  __shared__ float tile[32][33];
  int tx = threadIdx.x, ty = threadIdx.y;        // block (32, 8)
  int n0 = blockIdx.x * 32, k0 = blockIdx.y * 32;
  #pragma unroll
  for (int i = 0; i < 4; i++)
    tile[ty + 8 * i][tx] = in[(size_t)(k0 + ty + 8 * i) * NGATE + n0 + tx];
  __syncthreads();
  #pragma unroll
  for (int i = 0; i < 4; i++)
    out[(size_t)(n0 + ty + 8 * i) * HID + k0 + tx] = f2bf(tile[tx][ty + 8 * i]);
}

__global__ void init_ws(unsigned* __restrict__ himg0, unsigned* __restrict__ flags) {
  size_t i = (size_t)blockIdx.x * 256 + threadIdx.x;   // 16384 threads
  himg0[i] = 0u;                                       // HIMG_G/4 = 16384 dwords
  if (i < NBLK_B * FLAG_STRIDE) flags[i] = 0u;
}

// ---------------------------------------------------------------- Phase A
// C[16384][4096] bf16 = A[16384][1024] bf16  x  BT[4096][1024] bf16
__global__ __launch_bounds__(256) void gemm_xg(const unsigned short* __restrict__ A,
                                               const unsigned short* __restrict__ BT,
                                               unsigned short* __restrict__ C) {
  extern __shared__ char smem[];
  char* As = smem;                 // 128 rows * 80B (32 bf16 + 16B pad)
  char* Bs = smem + 10240;
  const int tid = threadIdx.x;
  const int lane = tid & 63, w = tid >> 6, q = lane >> 4, l16 = lane & 15;
  const int wm = w & 1, wn = w >> 1;
  const size_t m0 = (size_t)blockIdx.y * 128, n0 = (size_t)blockIdx.x * 128;

  f32x4_t acc[4][4];
  #pragma unroll
  for (int i = 0; i < 4; i++)
    #pragma unroll
    for (int j = 0; j < 4; j++) acc[i][j] = (f32x4_t){0.f, 0.f, 0.f, 0.f};

  for (int kk = 0; kk < 32; kk++) {
    const int k0 = kk * 32;
    #pragma unroll
    for (int h = 0; h < 2; h++) {
      int idx = tid + h * 256;              // 0..511
      int r = idx >> 2, ch = idx & 3;
      uint4 va = *(const uint4*)((const char*)A + ((m0 + r) * HID + k0) * 2 + ch * 16);
      *(uint4*)(As + r * 80 + ch * 16) = va;
      uint4 vb = *(const uint4*)((const char*)BT + ((n0 + r) * HID + k0) * 2 + ch * 16);
      *(uint4*)(Bs + r * 80 + ch * 16) = vb;
    }
    __syncthreads();
    bf16x8_t af[4], bf[4];
    #pragma unroll
    for (int mt = 0; mt < 4; mt++)
      af[mt] = *(const bf16x8_t*)(As + (wm * 64 + mt * 16 + l16) * 80 + q * 16);
    #pragma unroll
    for (int nt = 0; nt < 4; nt++)
      bf[nt] = *(const bf16x8_t*)(Bs + (wn * 64 + nt * 16 + l16) * 80 + q * 16);
    #pragma unroll
    for (int mt = 0; mt < 4; mt++)
      #pragma unroll
      for (int nt = 0; nt < 4; nt++)
        acc[mt][nt] = __builtin_amdgcn_mfma_f32_16x16x32_bf16(af[mt], bf[nt], acc[mt][nt], 0, 0, 0);
    __syncthreads();
  }

  // epilogue: stage C tile (bf16 [128][136]) through LDS for coalesced stores
  unsigned short* cst = (unsigned short*)smem;
  #pragma unroll
  for (int mt = 0; mt < 4; mt++)
    #pragma unroll
    for (int nt = 0; nt < 4; nt++)
      #pragma unroll
      for (int r = 0; r < 4; r++) {
        int m = wm * 64 + mt * 16 + q * 4 + r;
        int n = wn * 64 + nt * 16 + l16;
        cst[m * 136 + n] = f2bf(acc[mt][nt][r]);
      }
  __syncthreads();
  #pragma unroll
  for (int i = 0; i < 8; i++) {
    int idx = tid + i * 256;                // < 2048
    int row = idx >> 4, ch = idx & 15;
    uint4 v = *(const uint4*)((const char*)cst + row * 272 + ch * 16);
    *(uint4*)((char*)C + ((m0 + row) * NGATE + n0) * 2 + ch * 16) = v;
  }
}

// ---------------------------------------------------------------- Phase B
// Persistent recurrence. 128 blocks x 256 threads. Block owns 8 h-columns.
__global__ __launch_bounds__(256) void lstm_persistent(
    const unsigned short* __restrict__ xg,   // [16384][4096] bf16
    const unsigned short* __restrict__ whT,  // [4096][1024] bf16
    const float* __restrict__ bias,          // [4096]
    float* __restrict__ out,                 // [32][512][1024]
    unsigned short* hbuf,                    // 2 packed images, 65536B each
    unsigned* flags) {                       // [128] @ 16B stride
  extern __shared__ char smem[];
  char* w_lds = smem + W_OFF_L;
  char* h_lds = smem + H_OFF_L;
  float* gates = (float*)(smem + G_OFF_L);         // [32][33] f32

  const int tid = threadIdx.x;
  const int lane = tid & 63, w = tid >> 6, q = lane >> 4, l16 = lane & 15;
  const int Mt = w & 1, Nt = w >> 1;
  const int hcol0 = blockIdx.x * 8;
  const int b_ew = tid >> 3, j_ew = tid & 7;

  // pin Wh slice in LDS: lds row n (= g*8+j) <- whT row g*1024 + hcol0 + j
  for (int idx = tid; idx < 32 * 128; idx += 256) {
    int n = idx >> 7, ch = idx & 127;
    size_t gr = (size_t)((n >> 3) << 10) + hcol0 + (n & 7);
    uint4 v = *(const uint4*)((const char*)whT + gr * 2048 + ch * 16);
    *(uint4*)(w_lds + n * HROW_STRIDE + ch * 16) = v;
  }
  float bs[4];
  #pragma unroll
  for (int g = 0; g < 4; g++) bs[g] = bias[g * 1024 + hcol0 + j_ew];
  float c_st = 0.f;
  __syncthreads();

  for (int t = 0; t < SLEN; t++) {
    // prefetch xg for this step (no h dependency) — overlaps the flag wait
    unsigned short xgv[4];
    {
      const unsigned short* p = xg + ((size_t)((b_ew << 9) + t) << 12) + hcol0 + j_ew;
      xgv[0] = p[0]; xgv[1] = p[1024]; xgv[2] = p[2048]; xgv[3] = p[3072];
    }
    if (t > 0) {
      if (tid < NBLK_B) {
        const unsigned* fp = flags + tid * FLAG_STRIDE;
        while (__hip_atomic_load(fp, __ATOMIC_RELAXED, __HIP_MEMORY_SCOPE_AGENT) < (unsigned)t)
          __builtin_amdgcn_s_sleep(1);
      }
      __syncthreads();
      asm volatile("" ::: "memory");
    }
    // gather h image: 2x8B coherent loads -> one 16B LDS write per lane
    // (ds_write_b128, 64 lanes x 16B contiguous = conflict-free)
    {
      ull_t* src = (ull_t*)(hbuf + (size_t)(t & 1) * (HIMG_G / 2));
      #pragma unroll
      for (int k = 0; k < 16; k++) {
        int base = 2 * tid + k * 512;
        ull_t v0 = __hip_atomic_load(src + base, __ATOMIC_RELAXED,
                                     __HIP_MEMORY_SCOPE_AGENT);
        ull_t v1 = __hip_atomic_load(src + base + 1, __ATOMIC_RELAXED,
                                     __HIP_MEMORY_SCOPE_AGENT);
        int row = k * 2 + (tid >> 7);
        int col = (tid & 127) * 16;
        ull2_t wv; wv.x = v0; wv.y = v1;
        *(ull2_t*)(h_lds + row * HROW_STRIDE + col) = wv;
      }
    }
    __syncthreads();

    // gates[b][n] = sum_k h[b][k] * Wslice[k][n]
    f32x4_t acc0 = (f32x4_t){0.f, 0.f, 0.f, 0.f};
    f32x4_t acc1 = (f32x4_t){0.f, 0.f, 0.f, 0.f};
    const char* arow = h_lds + (Mt * 16 + l16) * HROW_STRIDE + q * 16;
    const char* brow = w_lds + (Nt * 16 + l16) * HROW_STRIDE + q * 16;
    #pragma unroll
    for (int kk = 0; kk < 32; kk += 2) {
      bf16x8_t a0 = *(const bf16x8_t*)(arow + kk * 64);
      bf16x8_t b0 = *(const bf16x8_t*)(brow + kk * 64);
      acc0 = __builtin_amdgcn_mfma_f32_16x16x32_bf16(a0, b0, acc0, 0, 0, 0);
      bf16x8_t a1 = *(const bf16x8_t*)(arow + kk * 64 + 64);
      bf16x8_t b1 = *(const bf16x8_t*)(brow + kk * 64 + 64);
      acc1 = __builtin_amdgcn_mfma_f32_16x16x32_bf16(a1, b1, acc1, 0, 0, 0);
    }
    #pragma unroll
    for (int r = 0; r < 4; r++) {
      int bb = Mt * 16 + q * 4 + r;
      int nn = Nt * 16 + l16;
      gates[bb * 33 + nn] = acc0[r] + acc1[r];
    }
    __syncthreads();

    // elementwise: thread owns (b_ew, j_ew)
    float gi = gates[b_ew * 33 + j_ew]      + bs[0] + bf2f(xgv[0]);
    float gf = gates[b_ew * 33 + 8 + j_ew]  + bs[1] + bf2f(xgv[1]);
    float gg = gates[b_ew * 33 + 16 + j_ew] + bs[2] + bf2f(xgv[2]);
    float go = gates[b_ew * 33 + 24 + j_ew] + bs[3] + bf2f(xgv[3]);
    float i_s = sigmoid_f(gi), f_s = sigmoid_f(gf);
    float g_t = tanh_f(gg), o_s = sigmoid_f(go);
    c_st = f_s * c_st + i_s * g_t;
    float h = o_s * tanh_f(c_st);

    // publish h: per-thread coherent 2B store, drain own wave's stores,
    // barrier (all waves drained), then RELAXED flag store. No wbl2/inv.
    unsigned short* hnext = hbuf + (size_t)((t + 1) & 1) * (HIMG_G / 2);
    __hip_atomic_store(hnext + b_ew * HID + hcol0 + j_ew, f2bf(h),
                       __ATOMIC_RELAXED, __HIP_MEMORY_SCOPE_AGENT);
    asm volatile("s_waitcnt vmcnt(0)" ::: "memory");
    __syncthreads();
    if (tid == 0)
      __hip_atomic_store(flags + blockIdx.x * FLAG_STRIDE, (unsigned)(t + 1),
                         __ATOMIC_RELAXED, __HIP_MEMORY_SCOPE_AGENT);
    // out store is NOT read by other blocks — keep it off the critical path
    out[((size_t)b_ew * SLEN + t) * HID + hcol0 + j_ew] = h;
  }
}

// ---------------------------------------------------------------- launcher
extern "C" void kernel_launch(void* const* d_in, const int* in_sizes, int n_in,
                              void* d_out, int out_size, void* d_ws, size_t ws_size,
                              hipStream_t stream) {
  const float* x    = (const float*)d_in[0];   // [32,512,1024]
  const float* wi   = (const float*)d_in[1];   // [1024,4096]
  const float* wh   = (const float*)d_in[2];   // [1024,4096]
  const float* bias = (const float*)d_in[3];   // [4096]
  float* out = (float*)d_out;

  char* ws = (char*)d_ws;
  unsigned short* xg   = (unsigned short*)(ws + XG_OFF);
  unsigned short* xb   = (unsigned short*)(ws + XB_OFF);
  unsigned short* wiT  = (unsigned short*)(ws + WIT_OFF);
  unsigned short* whT  = (unsigned short*)(ws + WHT_OFF);
  unsigned short* hbuf = (unsigned short*)(ws + HBUF_OFF);
  unsigned* flags      = (unsigned*)(ws + FLAGS_OFF);

  (void)hipFuncSetAttribute((const void*)lstm_persistent,
                            hipFuncAttributeMaxDynamicSharedMemorySize,
                            LDS_TOTAL);

  conv_x_bf16<<<16384, 256, 0, stream>>>(x, xb);
  transpose_w_bf16<<<dim3(128, 32), dim3(32, 8), 0, stream>>>(wi, wiT);
  transpose_w_bf16<<<dim3(128, 32), dim3(32, 8), 0, stream>>>(wh, whT);
  init_ws<<<64, 256, 0, stream>>>((unsigned*)hbuf, flags);
  gemm_xg<<<dim3(32, 128), 256, 34816, stream>>>(xb, wiT, xg);
  lstm_persistent<<<NBLK_B, 256, LDS_TOTAL, stream>>>(xg, whT, bias, out, hbuf, flags);
}